// Round 9
// baseline (278.584 us; speedup 1.0000x reference)
//
#include <hip/hip_runtime.h>

#define NTOT 12288
#define DIM  256
#define NB   2
#define BROWS 256         // rows per block (4 waves x 64)
#define CGRP  256         // cols per block (4 B-tiles of 64)
#define NT    4           // B-tiles per block
#define TILEB 32768       // bytes per B-tile in LDS (64 cols x 256 k fp16)
#define NGC   26          // col-group grid (covers nval <= 6656)
#define NRB   26          // row-block grid (covers ninv <= 6656)
#define GRID_TOT (NGC * NRB * NB)

typedef __attribute__((ext_vector_type(8))) _Float16 f16x8;
typedef __attribute__((ext_vector_type(16))) float f32x16;

// ---------- ordered-uint encoding for float atomicMax ----------
__device__ __forceinline__ unsigned toOrd(float f) {
    unsigned u = __float_as_uint(f);
    return (u & 0x80000000u) ? ~u : (u | 0x80000000u);
}
__device__ __forceinline__ float fromOrd(unsigned u) {
    unsigned b = (u & 0x80000000u) ? (u ^ 0x80000000u) : ~u;
    return __uint_as_float(b);
}
__device__ __forceinline__ void load_lds16(const void* g, void* l) {
    __builtin_amdgcn_global_load_lds(
        (const __attribute__((address_space(1))) unsigned int*)g,
        (__attribute__((address_space(3))) unsigned int*)l, 16, 0, 0);
}

// ws layout:
//   [0,64)            int cnts[6]: [0..1]=nval[b], [2..3]=ninv[b], [4]=done-counter
//   [64, +96KB)       int inv[NB*NTOT]   (dest -> source index)
//   [98368, +96KB)    unsigned maxsim[NB*NTOT]
//   [262144, +12.6MB) ushort pk[NB][384 panels][16 chunks][512] fragment-linear fp16

// ---------------- kernel 1: per-batch scan (prefetched) -> inverse perm, init maxsim ----------------
__global__ __launch_bounds__(1024) void k_scan(
    const int* __restrict__ mask, int* __restrict__ inv,
    unsigned* __restrict__ maxsim, int* __restrict__ cnts)
{
    int b = blockIdx.x;
    int tid = threadIdx.x;
    int lane = tid & 63, w = tid >> 6;        // 16 waves
    __shared__ int wsum[16];

    if (b == 0 && tid == 0) ((unsigned*)cnts)[4] = 0u;   // done-counter for k_gemm

    int mv[12];
    #pragma unroll
    for (int j = 0; j < 12; j++) mv[j] = mask[b * NTOT + j * 1024 + tid] ? 1 : 0;

    int running = 0;
    #pragma unroll
    for (int j = 0; j < 12; j++) {
        int i = j * 1024 + tid;
        int m = mv[j];
        int v = m;
        #pragma unroll
        for (int off = 1; off < 64; off <<= 1) {
            int t = __shfl_up(v, off);
            if (lane >= off) v += t;
        }
        if (lane == 63) wsum[w] = v;
        __syncthreads();
        int woff = 0, ctot = 0;
        #pragma unroll
        for (int k = 0; k < 16; k++) { int s = wsum[k]; ctot += s; if (k < w) woff += s; }
        int ex = running + woff + v - m;           // exclusive prefix of "valid"
        int d = m ? ex : (NTOT - 1 - (i - ex));    // invalid packed from the back
        inv[b * NTOT + d] = i;
        maxsim[b * NTOT + i] = 0u;                 // decodes to NaN -> never confident
        running += ctot;
        __syncthreads();
    }
    if (tid == 0) { cnts[b] = running; cnts[NB + b] = NTOT - running; }
}

// ------- kernel 2: gather + normalize + fragment-layout via LDS, contiguous global writes -------
__global__ __launch_bounds__(256) void k_norm(
    const float* __restrict__ feat, const int* __restrict__ inv, ushort* __restrict__ pk)
{
    __shared__ __align__(16) ushort pan[16][512];   // one 32-row panel (32x256 fp16) = 16 KB
    int blk = blockIdx.x;
    int b = blk / (NTOT / 32);
    int panel = blk % (NTOT / 32);
    int tid = threadIdx.x;
    int r = tid >> 3, c = tid & 7;           // 32 rows x 8 k-slices
    int i = inv[b * NTOT + panel * 32 + r];
    const float* src = feat + ((size_t)b * NTOT + i) * DIM + c * 32;

    float x[32]; float ss = 0.f;
    #pragma unroll
    for (int j = 0; j < 8; j++) {
        float4 v = *(const float4*)(src + j * 4);
        x[j*4+0] = v.x; x[j*4+1] = v.y; x[j*4+2] = v.z; x[j*4+3] = v.w;
        ss += v.x*v.x + v.y*v.y + v.z*v.z + v.w*v.w;
    }
    ss += __shfl_xor(ss, 1); ss += __shfl_xor(ss, 2); ss += __shfl_xor(ss, 4);
    float invn = 1.0f / fmaxf(sqrtf(ss), 1e-12f);

    #pragma unroll
    for (int g = 0; g < 4; g++) {            // fragment positions in LDS
        f16x8 hv;
        #pragma unroll
        for (int e = 0; e < 8; e++) hv[e] = (_Float16)(x[g*8+e] * invn);
        int kc = c * 2 + (g >> 1), kh = g & 1;
        *(f16x8*)&pan[kc][(kh * 32 + r) * 8] = hv;
    }
    __syncthreads();

    // contiguous copy-out: 16KB panel = 1024 x 16B  (j<4 — NOT 8: panel is 16KB)
    f16x8* dst = (f16x8*)(pk + (size_t)b * NTOT * DIM + (size_t)panel * 16 * 512);
    const f16x8* srcl = (const f16x8*)pan;
    #pragma unroll
    for (int j = 0; j < 4; j++) dst[tid + j * 256] = srcl[tid + j * 256];
}

// -------- kernel 3: A-in-register (64 rows/wave), B-streaming fp16 MFMA GEMM + folded finalize --------
__global__ __launch_bounds__(256, 2) void k_gemm(
    const ushort* __restrict__ pk, unsigned* __restrict__ maxsim,
    int* __restrict__ cnts, float* __restrict__ out)
{
    __shared__ __align__(16) char smem[2 * TILEB];   // 64 KiB: 2-deep B-tile ring

    int b = blockIdx.z;
    int nval = cnts[b];
    int ninv = cnts[NB + b];
    int bx = blockIdx.x;     // col group
    int by = blockIdx.y;     // row block (from back)
    int tid = threadIdx.x, lane = tid & 63, w = tid >> 6;   // 4 waves, wave w: rows +w*64
    unsigned* donecnt = (unsigned*)cnts + 4;

    bool active = (bx * CGRP < nval) && (by * BROWS < ninv);
    if (active) {
        int rowA0 = NTOT - (by + 1) * BROWS;
        int colG0 = bx * CGRP;
        int pA0 = rowA0 >> 5, pBg = colG0 >> 5;
        const ushort* pb = pk + (size_t)b * NTOT * DIM;

        // ---- A resident: 2 row-tiles x 16 k-slices = 128 VGPR ----
        f16x8 a[2][16];
        {
            const ushort* abase = pb + (size_t)(pA0 + w * 2) * 16 * 512 + lane * 8;
            #pragma unroll
            for (int mt = 0; mt < 2; mt++)
                #pragma unroll
                for (int ks = 0; ks < 16; ks++)
                    a[mt][ks] = *(const f16x8*)(abase + (size_t)(mt * 16 + ks) * 512);
        }
        __builtin_amdgcn_sched_barrier(0);

        // stage B-tile t (64 cols = 2 panels = 32 chunks of 1KB); wave w: chunks w*8..w*8+7
#define STAGE(t) { const int bo_ = ((t) & 1) * TILEB; const int p0_ = pBg + (t) * 2;  \
    _Pragma("unroll")                                                                 \
    for (int c_ = 0; c_ < 8; c_++) {                                                  \
        int c__ = w * 8 + c_;                                                         \
        const ushort* g__ = pb + ((size_t)(p0_ + (c__ >> 4)) * 16 + (c__ & 15)) * 512 + lane * 8; \
        load_lds16(g__, smem + bo_ + c__ * 1024);                                     \
    }                                                                                 \
    __builtin_amdgcn_sched_barrier(0); }

        STAGE(0); STAGE(1);

        float mrow[2][16];
        #pragma unroll
        for (int mt = 0; mt < 2; mt++)
            #pragma unroll
            for (int rr = 0; rr < 16; rr++) mrow[mt][rr] = -INFINITY;

        const f32x16 zacc = {};

        #pragma unroll
        for (int t = 0; t < NT; t++) {
            if (t < NT - 1) asm volatile("s_waitcnt vmcnt(8)" ::: "memory");
            else            asm volatile("s_waitcnt vmcnt(0)" ::: "memory");
            __builtin_amdgcn_s_barrier();
            __builtin_amdgcn_sched_barrier(0);

            const char* sb = smem + (t & 1) * TILEB;
            #pragma unroll
            for (int nt = 0; nt < 2; nt++) {
                f32x16 acc0 = zacc, acc1 = zacc;
                #pragma unroll
                for (int kq = 0; kq < 4; kq++) {
                    f16x8 bg[4];
                    #pragma unroll
                    for (int k4 = 0; k4 < 4; k4++)
                        bg[k4] = *(const f16x8*)(sb + (nt * 16 + kq * 4 + k4) * 1024 + lane * 16);
                    __builtin_amdgcn_s_setprio(1);
                    #pragma unroll
                    for (int k4 = 0; k4 < 4; k4++) {
                        acc0 = __builtin_amdgcn_mfma_f32_32x32x16_f16(a[0][kq*4+k4], bg[k4], acc0, 0, 0, 0);
                        acc1 = __builtin_amdgcn_mfma_f32_32x32x16_f16(a[1][kq*4+k4], bg[k4], acc1, 0, 0, 0);
                    }
                    __builtin_amdgcn_s_setprio(0);
                }
                int cg = colG0 + t * 64 + nt * 32 + (lane & 31);
                bool cv = cg < nval;
                #pragma unroll
                for (int rr = 0; rr < 16; rr++) {
                    mrow[0][rr] = fmaxf(mrow[0][rr], cv ? acc0[rr] : -INFINITY);
                    mrow[1][rr] = fmaxf(mrow[1][rr], cv ? acc1[rr] : -INFINITY);
                }
            }
            __builtin_amdgcn_s_barrier();     // all waves done reading buf (t&1)
            if (t + 2 < NT) STAGE(t + 2);
        }
#undef STAGE

        // ---- epilogue: butterfly over 32-lane col groups, one atomic per row ----
        #pragma unroll
        for (int off = 1; off <= 16; off <<= 1)
            #pragma unroll
            for (int mt = 0; mt < 2; mt++)
                #pragma unroll
                for (int rr = 0; rr < 16; rr++)
                    mrow[mt][rr] = fmaxf(mrow[mt][rr], __shfl_xor(mrow[mt][rr], off));

        int cl = lane & 31, hh = lane >> 5;
        if (cl == 0) {
            #pragma unroll
            for (int mt = 0; mt < 2; mt++)
                #pragma unroll
                for (int rr = 0; rr < 16; rr++) {
                    int rowg = rowA0 + w * 64 + mt * 32 + (rr & 3) + 8 * (rr >> 2) + 4 * hh;
                    atomicMax(maxsim + (size_t)b * NTOT + rowg, toOrd(mrow[mt][rr]));
                }
        }
    }

    // ---- folded finalize: last block to arrive reduces maxsim -> out[0] ----
    __threadfence();
    __syncthreads();                               // smem reuse safe below
    unsigned* sflag = (unsigned*)smem;
    if (tid == 0) *sflag = atomicAdd(donecnt, 1u);
    __syncthreads();
    if (*sflag == GRID_TOT - 1) {
        __threadfence();
        float* ssum = (float*)(smem + 16);
        int*   scnt = (int*)(smem + 32);
        if (tid < NB) { ssum[tid] = 0.0f; scnt[tid] = 0; }
        __syncthreads();
        for (int bb = 0; bb < NB; bb++) {
            int ninv2 = cnts[NB + bb];
            float ls = 0.0f; int lc = 0;
            for (int i = tid; i < ninv2; i += 256) {
                int r = NTOT - ninv2 + i;
                float ms = fromOrd(maxsim[(size_t)bb * NTOT + r]);
                if (ms > 0.8f) { ls += 1.0f - ms; lc++; }   // NaN-safe
            }
            #pragma unroll
            for (int off = 32; off; off >>= 1) {
                ls += __shfl_xor(ls, off);
                lc += __shfl_xor(lc, off);
            }
            if ((tid & 63) == 0) { atomicAdd(&ssum[bb], ls); atomicAdd(&scnt[bb], lc); }
        }
        __syncthreads();
        if (tid == 0) {
            float tl = 0.0f, tp = 0.0f;
            for (int bb = 0; bb < NB; bb++) {
                int nval2 = cnts[bb], ninv2 = cnts[NB + bb], nc = scnt[bb];
                bool act = (nc > 0) && (nval2 > 0) && (ninv2 > 0);
                if (act) {
                    float pseudo = ssum[bb] / (float)(nc > 0 ? nc : 1);
                    tl += pseudo * (float)ninv2;
                    tp += (float)ninv2;
                }
            }
            out[0] = (tp > 0.0f) ? (0.01f * tl / tp) : 0.0f;
        }
    }
}

extern "C" void kernel_launch(void* const* d_in, const int* in_sizes, int n_in,
                              void* d_out, int out_size, void* d_ws, size_t ws_size,
                              hipStream_t stream)
{
    const float* feat = (const float*)d_in[0];
    const int*   mask = (const int*)d_in[1];

    char* ws = (char*)d_ws;
    int*      cnts   = (int*)ws;
    int*      inv    = (int*)(ws + 64);
    unsigned* maxsim = (unsigned*)(ws + 98368);
    ushort*   pk     = (ushort*)(ws + 262144);

    hipLaunchKernelGGL(k_scan, dim3(NB), dim3(1024), 0, stream, mask, inv, maxsim, cnts);
    hipLaunchKernelGGL(k_norm, dim3(NB * (NTOT / 32)), dim3(256), 0, stream, feat, inv, pk);
    hipLaunchKernelGGL(k_gemm, dim3(NGC, NRB, NB), dim3(256), 0, stream,
                       pk, maxsim, cnts, (float*)d_out);
}